// Round 4
// baseline (921.927 us; speedup 1.0000x reference)
//
#include <hip/hip_runtime.h>
#include <math.h>

typedef unsigned int u32;

#define N0V 500000
#define N1V 50000
#define N2V 4096
#define E0V 1280000
#define E1V 40960
#define INF 128
#define HIDF 256
#define OUTF 47

// ---------------- CSR build: histogram ----------------
__global__ __launch_bounds__(256) void hist_k(
    const int* __restrict__ dst0, const int* __restrict__ dst1,
    int* __restrict__ hist0, int* __restrict__ hist1) {
  int gid = blockIdx.x * 256 + threadIdx.x;
  if (gid < E0V) {
    atomicAdd(&hist0[dst0[gid]], 1);
  } else if (gid < E0V + E1V) {
    atomicAdd(&hist1[dst1[gid - E0V]], 1);
  }
}

// ---------------- CSR build: prefix scan (single block) ----------------
__global__ __launch_bounds__(1024) void scan_k(
    const int* __restrict__ hist0, const int* __restrict__ hist1,
    int* __restrict__ off0, int* __restrict__ cur0,
    int* __restrict__ off1, int* __restrict__ cur1) {
  __shared__ int sums[1024];
  const int t = threadIdx.x;
  {
    const int N = 50000, C = 49;
    int lo = t * C;
    int hi = lo + C; if (hi > N) hi = N;
    int s = 0;
    for (int i = lo; i < hi; i++) s += hist0[i];
    sums[t] = s;
    __syncthreads();
    for (int off = 1; off < 1024; off <<= 1) {
      int v = (t >= off) ? sums[t - off] : 0;
      __syncthreads();
      sums[t] += v;
      __syncthreads();
    }
    int run = sums[t] - s;
    for (int i = lo; i < hi; i++) {
      off0[i] = run; cur0[i] = run;
      run += hist0[i];
    }
    if (t == 1023) off0[N] = sums[1023];
    __syncthreads();
  }
  {
    const int N = 4096, C = 4;
    int lo = t * C;
    int hi = lo + C; if (hi > N) hi = N;
    int s = 0;
    for (int i = lo; i < hi; i++) s += hist1[i];
    sums[t] = s;
    __syncthreads();
    for (int off = 1; off < 1024; off <<= 1) {
      int v = (t >= off) ? sums[t - off] : 0;
      __syncthreads();
      sums[t] += v;
      __syncthreads();
    }
    int run = sums[t] - s;
    for (int i = lo; i < hi; i++) {
      off1[i] = run; cur1[i] = run;
      run += hist1[i];
    }
    if (t == 1023) off1[N] = sums[1023];
  }
}

// ---------------- CSR build: scatter edge source ids ----------------
__global__ __launch_bounds__(256) void scatteridx_k(
    const int* __restrict__ src0, const int* __restrict__ dst0,
    const int* __restrict__ src1, const int* __restrict__ dst1,
    int* __restrict__ cur0, int* __restrict__ cur1,
    int* __restrict__ esrc0, int* __restrict__ esrc1) {
  int gid = blockIdx.x * 256 + threadIdx.x;
  if (gid < E0V) {
    int pos = atomicAdd(&cur0[dst0[gid]], 1);
    esrc0[pos] = src0[gid];
  } else if (gid < E0V + E1V) {
    int g = gid - E0V;
    int pos = atomicAdd(&cur1[dst1[g]], 1);
    esrc1[pos] = src1[g];
  }
}

// ---------------- x -> packed bf16 conversion ----------------
__device__ __forceinline__ u32 bf16rne(float f) {
  u32 u = __float_as_uint(f);
  return (u + 0x7fffu + ((u >> 16) & 1u)) >> 16;
}
__device__ __forceinline__ u32 pk2(float lo, float hi) {
  return bf16rne(lo) | (bf16rne(hi) << 16);
}

// 64,000,000 floats total = 8,000,000 chunks of 8 floats -> 31250 blocks x 256
__global__ __launch_bounds__(256) void conv_k(
    const float4* __restrict__ x4, uint4* __restrict__ xh4) {
  int gid = blockIdx.x * 256 + threadIdx.x;
  if (gid >= 8000000) return;
  float4 a = x4[2 * gid];
  float4 b = x4[2 * gid + 1];
  uint4 o;
  o.x = pk2(a.x, a.y);
  o.y = pk2(a.z, a.w);
  o.z = pk2(b.x, b.y);
  o.w = pk2(b.z, b.w);
  xh4[gid] = o;
}

// ---------------- layer 0 fused (bf16 gather path) ----------------
// 16 rows/block, 4 waves; wave gathers 4 rows from packed-bf16 x.
__global__ __launch_bounds__(256) void dense0_fused_bf16(
    const float* __restrict__ x, const u32* __restrict__ xh,
    const int* __restrict__ off0, const int* __restrict__ esrc0,
    const float* __restrict__ Wl, const float* __restrict__ bl,
    const float* __restrict__ Wr, float* __restrict__ h) {
  __shared__ float a_s[16 * 128];
  __shared__ float x_s[16 * 128];
  const int tid = threadIdx.x;
  const int base = blockIdx.x * 16;
  const int wave = tid >> 6;
  const int lane = tid & 63;

  for (int idx = tid; idx < 16 * 128; idx += 256)
    x_s[idx] = x[base * 128 + idx];

  for (int q = 0; q < 4; q++) {
    int r = wave * 4 + q;
    int row = base + r;
    int s0 = off0[row];
    int n = off0[row + 1] - s0;
    float accL = 0.f, accH = 0.f;
    for (int c0 = 0; c0 < n; c0 += 64) {
      int m = n - c0; if (m > 64) m = 64;
      int myid = (lane < m) ? esrc0[s0 + c0 + lane] : 0;
      int j = 0;
      for (; j + 8 <= m; j += 8) {
        int i0 = __shfl(myid, j + 0, 64);
        int i1 = __shfl(myid, j + 1, 64);
        int i2 = __shfl(myid, j + 2, 64);
        int i3 = __shfl(myid, j + 3, 64);
        int i4 = __shfl(myid, j + 4, 64);
        int i5 = __shfl(myid, j + 5, 64);
        int i6 = __shfl(myid, j + 6, 64);
        int i7 = __shfl(myid, j + 7, 64);
        u32 u0 = xh[i0 * 64 + lane];
        u32 u1 = xh[i1 * 64 + lane];
        u32 u2 = xh[i2 * 64 + lane];
        u32 u3 = xh[i3 * 64 + lane];
        u32 u4 = xh[i4 * 64 + lane];
        u32 u5 = xh[i5 * 64 + lane];
        u32 u6 = xh[i6 * 64 + lane];
        u32 u7 = xh[i7 * 64 + lane];
        accL += __uint_as_float(u0 << 16) + __uint_as_float(u1 << 16) +
                __uint_as_float(u2 << 16) + __uint_as_float(u3 << 16) +
                __uint_as_float(u4 << 16) + __uint_as_float(u5 << 16) +
                __uint_as_float(u6 << 16) + __uint_as_float(u7 << 16);
        accH += __uint_as_float(u0 & 0xffff0000u) + __uint_as_float(u1 & 0xffff0000u) +
                __uint_as_float(u2 & 0xffff0000u) + __uint_as_float(u3 & 0xffff0000u) +
                __uint_as_float(u4 & 0xffff0000u) + __uint_as_float(u5 & 0xffff0000u) +
                __uint_as_float(u6 & 0xffff0000u) + __uint_as_float(u7 & 0xffff0000u);
      }
      for (; j < m; j++) {
        int sid = __shfl(myid, j, 64);
        u32 u = xh[sid * 64 + lane];
        accL += __uint_as_float(u << 16);
        accH += __uint_as_float(u & 0xffff0000u);
      }
    }
    float rinv = 1.f / fmaxf((float)n, 1.f);
    a_s[r * 128 + 2 * lane] = accL * rinv;
    a_s[r * 128 + 2 * lane + 1] = accH * rinv;
  }
  __syncthreads();

  const int j = tid;
  float acc[16];
#pragma unroll
  for (int rr = 0; rr < 16; rr++) acc[rr] = 0.0f;
  for (int k = 0; k < 128; k++) {
    float wl = Wl[k * 256 + j];
    float wr = Wr[k * 256 + j];
#pragma unroll
    for (int rr = 0; rr < 16; rr++)
      acc[rr] += a_s[rr * 128 + k] * wl + x_s[rr * 128 + k] * wr;
  }
  float b = bl[j];
#pragma unroll
  for (int rr = 0; rr < 16; rr++)
    h[(base + rr) * 256 + j] = fmaxf(acc[rr] + b, 0.0f);
}

// ---------------- layer 0 fused (fp32 gather fallback) ----------------
__global__ __launch_bounds__(256) void dense0_fused_f32(
    const float* __restrict__ x, const int* __restrict__ off0,
    const int* __restrict__ esrc0, const float* __restrict__ Wl,
    const float* __restrict__ bl, const float* __restrict__ Wr,
    float* __restrict__ h) {
  __shared__ float a_s[16 * 128];
  __shared__ float x_s[16 * 128];
  const int tid = threadIdx.x;
  const int base = blockIdx.x * 16;
  const int wave = tid >> 6;
  const int lane = tid & 63;

  for (int idx = tid; idx < 16 * 128; idx += 256)
    x_s[idx] = x[base * 128 + idx];

  for (int q = 0; q < 4; q++) {
    int r = wave * 4 + q;
    int row = base + r;
    int s0 = off0[row];
    int n = off0[row + 1] - s0;
    float acc0 = 0.f, acc1 = 0.f;
    for (int c0 = 0; c0 < n; c0 += 64) {
      int m = n - c0; if (m > 64) m = 64;
      int myid = (lane < m) ? esrc0[s0 + c0 + lane] : 0;
      int j = 0;
      for (; j + 4 <= m; j += 4) {
        int i0 = __shfl(myid, j + 0, 64);
        int i1 = __shfl(myid, j + 1, 64);
        int i2 = __shfl(myid, j + 2, 64);
        int i3 = __shfl(myid, j + 3, 64);
        const float* r0 = x + (long long)i0 * INF;
        const float* r1 = x + (long long)i1 * INF;
        const float* r2 = x + (long long)i2 * INF;
        const float* r3 = x + (long long)i3 * INF;
        float a0 = r0[lane], b0 = r0[lane + 64];
        float a1 = r1[lane], b1 = r1[lane + 64];
        float a2 = r2[lane], b2 = r2[lane + 64];
        float a3 = r3[lane], b3 = r3[lane + 64];
        acc0 += a0 + a1 + a2 + a3;
        acc1 += b0 + b1 + b2 + b3;
      }
      for (; j < m; j++) {
        int sid = __shfl(myid, j, 64);
        const float* xr = x + (long long)sid * INF;
        acc0 += xr[lane];
        acc1 += xr[lane + 64];
      }
    }
    float rinv = 1.f / fmaxf((float)n, 1.f);
    a_s[r * 128 + lane] = acc0 * rinv;
    a_s[r * 128 + lane + 64] = acc1 * rinv;
  }
  __syncthreads();

  const int j = tid;
  float acc[16];
#pragma unroll
  for (int rr = 0; rr < 16; rr++) acc[rr] = 0.0f;
  for (int k = 0; k < 128; k++) {
    float wl = Wl[k * 256 + j];
    float wr = Wr[k * 256 + j];
#pragma unroll
    for (int rr = 0; rr < 16; rr++)
      acc[rr] += a_s[rr * 128 + k] * wl + x_s[rr * 128 + k] * wr;
  }
  float b = bl[j];
#pragma unroll
  for (int rr = 0; rr < 16; rr++)
    h[(base + rr) * 256 + j] = fmaxf(acc[rr] + b, 0.0f);
}

// ---------------- layer 1: fused gather-mean + dense + log_softmax ----------------
__global__ __launch_bounds__(64) void final_fused(
    const float* __restrict__ h, const int* __restrict__ off1,
    const int* __restrict__ esrc1, const float* __restrict__ Wl,
    const float* __restrict__ bl, const float* __restrict__ Wr,
    float* __restrict__ out) {
  __shared__ float a_s[256];
  __shared__ float h_s[256];
  const int i = blockIdx.x;
  const int lane = threadIdx.x;

  int s0 = off1[i];
  int n = off1[i + 1] - s0;
  float acc0 = 0.f, acc1 = 0.f, acc2 = 0.f, acc3 = 0.f;
  for (int c0 = 0; c0 < n; c0 += 64) {
    int m = n - c0; if (m > 64) m = 64;
    int myid = (lane < m) ? esrc1[s0 + c0 + lane] : 0;
    int j = 0;
    for (; j + 2 <= m; j += 2) {
      int i0 = __shfl(myid, j, 64);
      int i1 = __shfl(myid, j + 1, 64);
      const float* r0 = h + (long long)i0 * HIDF;
      const float* r1 = h + (long long)i1 * HIDF;
      float a0 = r0[lane], b0 = r0[lane + 64], c0v = r0[lane + 128], d0 = r0[lane + 192];
      float a1 = r1[lane], b1 = r1[lane + 64], c1v = r1[lane + 128], d1 = r1[lane + 192];
      acc0 += a0 + a1; acc1 += b0 + b1; acc2 += c0v + c1v; acc3 += d0 + d1;
    }
    for (; j < m; j++) {
      int sid = __shfl(myid, j, 64);
      const float* hr = h + (long long)sid * HIDF;
      acc0 += hr[lane];
      acc1 += hr[lane + 64];
      acc2 += hr[lane + 128];
      acc3 += hr[lane + 192];
    }
  }
  float rinv = 1.f / fmaxf((float)n, 1.f);
  a_s[lane] = acc0 * rinv;
  a_s[lane + 64] = acc1 * rinv;
  a_s[lane + 128] = acc2 * rinv;
  a_s[lane + 192] = acc3 * rinv;
  const float* ht = h + (long long)i * HIDF;
  h_s[lane] = ht[lane];
  h_s[lane + 64] = ht[lane + 64];
  h_s[lane + 128] = ht[lane + 128];
  h_s[lane + 192] = ht[lane + 192];
  __syncthreads();

  float val = -INFINITY;
  if (lane < OUTF) {
    float acc = bl[lane];
    for (int k = 0; k < 256; k++)
      acc += a_s[k] * Wl[k * OUTF + lane] + h_s[k] * Wr[k * OUTF + lane];
    val = acc;
  }

  float mx = val;
  for (int off = 32; off >= 1; off >>= 1) mx = fmaxf(mx, __shfl_xor(mx, off, 64));
  float ex = (lane < OUTF) ? expf(val - mx) : 0.0f;
  float ssum = ex;
  for (int off = 32; off >= 1; off >>= 1) ssum += __shfl_xor(ssum, off, 64);

  if (lane < OUTF) out[i * OUTF + lane] = val - mx - logf(ssum);
}

extern "C" void kernel_launch(void* const* d_in, const int* in_sizes, int n_in,
                              void* d_out, int out_size, void* d_ws, size_t ws_size,
                              hipStream_t stream) {
  const float* x   = (const float*)d_in[0];
  const float* Wl0 = (const float*)d_in[1];
  const float* bl0 = (const float*)d_in[2];
  const float* Wr0 = (const float*)d_in[3];
  const float* Wl1 = (const float*)d_in[4];
  const float* bl1 = (const float*)d_in[5];
  const float* Wr1 = (const float*)d_in[6];
  const int* src0  = (const int*)d_in[7];
  const int* dst0  = (const int*)d_in[8];
  const int* src1  = (const int*)d_in[9];
  const int* dst1  = (const int*)d_in[10];
  float* out = (float*)d_out;

  // workspace layout (bytes):
  //   hist0 @ 0           200,000
  //   hist1 @ 200,064      16,384   (memset covers [0, 216,448))
  //   off0  @ 216,576     200,004
  //   cur0  @ 416,768     200,000
  //   off1  @ 616,960      16,388
  //   cur1  @ 633,600      16,384
  //   esrc0 @ 650,240   5,120,000
  //   esrc1 @ 5,770,240   163,840
  //   h     @ 5,934,080  51,200,000  (end 57,134,080)
  //   xh    @ 57,134,080 128,000,000 (end 185,134,080) -- bf16 path only
  char* ws = (char*)d_ws;
  int* hist0 = (int*)(ws);
  int* hist1 = (int*)(ws + 200064);
  int* off0  = (int*)(ws + 216576);
  int* cur0  = (int*)(ws + 416768);
  int* off1  = (int*)(ws + 616960);
  int* cur1  = (int*)(ws + 633600);
  int* esrc0 = (int*)(ws + 650240);
  int* esrc1 = (int*)(ws + 5770240);
  float* h   = (float*)(ws + 5934080);
  u32* xh    = (u32*)(ws + 57134080);

  const bool use_bf16 = (ws_size >= (size_t)185134080);

  hipMemsetAsync(ws, 0, 216448, stream);

  const int gridE = (E0V + E1V + 255) / 256;
  hist_k<<<gridE, 256, 0, stream>>>(dst0, dst1, hist0, hist1);
  scan_k<<<1, 1024, 0, stream>>>(hist0, hist1, off0, cur0, off1, cur1);
  scatteridx_k<<<gridE, 256, 0, stream>>>(src0, dst0, src1, dst1,
                                          cur0, cur1, esrc0, esrc1);
  if (use_bf16) {
    // 64M floats / 8 per thread = 8,000,000 threads -> 31250 blocks of 256
    conv_k<<<31250, 256, 0, stream>>>((const float4*)x, (uint4*)xh);
    dense0_fused_bf16<<<N1V / 16, 256, 0, stream>>>(x, xh, off0, esrc0,
                                                    Wl0, bl0, Wr0, h);
  } else {
    dense0_fused_f32<<<N1V / 16, 256, 0, stream>>>(x, off0, esrc0,
                                                   Wl0, bl0, Wr0, h);
  }
  final_fused<<<N2V, 64, 0, stream>>>(h, off1, esrc1, Wl1, bl1, Wr1, out);
}

// Round 5
// 766.662 us; speedup vs baseline: 1.2025x; 1.2025x over previous
//
#include <hip/hip_runtime.h>
#include <math.h>

typedef unsigned int u32;
typedef short bf16x8 __attribute__((ext_vector_type(8)));   // 8 bf16 bit-patterns
typedef float f32x4 __attribute__((ext_vector_type(4)));

#define N0V 500000
#define N1V 50000
#define N2V 4096
#define E0V 1280000
#define E1V 40960
#define INF 128
#define HIDF 256
#define OUTF 47

// ---------------- CSR build: histogram ----------------
__global__ __launch_bounds__(256) void hist_k(
    const int* __restrict__ dst0, const int* __restrict__ dst1,
    int* __restrict__ hist0, int* __restrict__ hist1) {
  int gid = blockIdx.x * 256 + threadIdx.x;
  if (gid < E0V) {
    atomicAdd(&hist0[dst0[gid]], 1);
  } else if (gid < E0V + E1V) {
    atomicAdd(&hist1[dst1[gid - E0V]], 1);
  }
}

// ---------------- CSR build: prefix scan (single block) ----------------
__global__ __launch_bounds__(1024) void scan_k(
    const int* __restrict__ hist0, const int* __restrict__ hist1,
    int* __restrict__ off0, int* __restrict__ cur0,
    int* __restrict__ off1, int* __restrict__ cur1) {
  __shared__ int sums[1024];
  const int t = threadIdx.x;
  {
    const int N = 50000, C = 49;
    int lo = t * C;
    int hi = lo + C; if (hi > N) hi = N;
    int s = 0;
    for (int i = lo; i < hi; i++) s += hist0[i];
    sums[t] = s;
    __syncthreads();
    for (int off = 1; off < 1024; off <<= 1) {
      int v = (t >= off) ? sums[t - off] : 0;
      __syncthreads();
      sums[t] += v;
      __syncthreads();
    }
    int run = sums[t] - s;
    for (int i = lo; i < hi; i++) {
      off0[i] = run; cur0[i] = run;
      run += hist0[i];
    }
    if (t == 1023) off0[N] = sums[1023];
    __syncthreads();
  }
  {
    const int N = 4096, C = 4;
    int lo = t * C;
    int hi = lo + C; if (hi > N) hi = N;
    int s = 0;
    for (int i = lo; i < hi; i++) s += hist1[i];
    sums[t] = s;
    __syncthreads();
    for (int off = 1; off < 1024; off <<= 1) {
      int v = (t >= off) ? sums[t - off] : 0;
      __syncthreads();
      sums[t] += v;
      __syncthreads();
    }
    int run = sums[t] - s;
    for (int i = lo; i < hi; i++) {
      off1[i] = run; cur1[i] = run;
      run += hist1[i];
    }
    if (t == 1023) off1[N] = sums[1023];
  }
}

// ---------------- CSR build: scatter edge source ids ----------------
__global__ __launch_bounds__(256) void scatteridx_k(
    const int* __restrict__ src0, const int* __restrict__ dst0,
    const int* __restrict__ src1, const int* __restrict__ dst1,
    int* __restrict__ cur0, int* __restrict__ cur1,
    int* __restrict__ esrc0, int* __restrict__ esrc1) {
  int gid = blockIdx.x * 256 + threadIdx.x;
  if (gid < E0V) {
    int pos = atomicAdd(&cur0[dst0[gid]], 1);
    esrc0[pos] = src0[gid];
  } else if (gid < E0V + E1V) {
    int g = gid - E0V;
    int pos = atomicAdd(&cur1[dst1[g]], 1);
    esrc1[pos] = src1[g];
  }
}

// ---------------- bf16 helpers ----------------
__device__ __forceinline__ u32 bf16rne(float f) {
  u32 u = __float_as_uint(f);
  return (u + 0x7fffu + ((u >> 16) & 1u)) >> 16;
}
__device__ __forceinline__ u32 pk2(float lo, float hi) {
  return bf16rne(lo) | (bf16rne(hi) << 16);
}

// x (fp32) -> packed bf16; 64M floats = 8M chunks of 8 -> 31250 blocks x 256
__global__ __launch_bounds__(256) void conv_k(
    const float4* __restrict__ x4, uint4* __restrict__ xh4) {
  int gid = blockIdx.x * 256 + threadIdx.x;
  if (gid >= 8000000) return;
  float4 a = x4[2 * gid];
  float4 b = x4[2 * gid + 1];
  uint4 o;
  o.x = pk2(a.x, a.y);
  o.y = pk2(a.z, a.w);
  o.z = pk2(b.x, b.y);
  o.w = pk2(b.z, b.w);
  xh4[gid] = o;
}

// ---------------- pack stacked [Wl0;Wr0] into MFMA B-fragment order ----------------
// B-frag for 16x16x32: lane holds B[k = s*32 + (lane>>4)*8 + j][n = t*16 + (lane&15)],
// j = 0..7. Layout: Wf[((t*8+s)*64 + lane)*8 + j] as bf16.
// Total 256*256 bf16 = 32768 u32 -> 128 blocks x 256 threads, 1 u32 each.
__global__ __launch_bounds__(256) void packW0_k(
    const float* __restrict__ Wl, const float* __restrict__ Wr,
    u32* __restrict__ Wf) {
  int gid = blockIdx.x * 256 + threadIdx.x;  // 0..32767
  int e0 = 2 * gid;
  int j = e0 & 7;            // even
  int lane = (e0 >> 3) & 63;
  int sq = e0 >> 9;
  int s = sq & 7;
  int t = sq >> 3;
  int n = t * 16 + (lane & 15);
  int k0 = s * 32 + (lane >> 4) * 8 + j;
  float v0 = (k0 < 128) ? Wl[k0 * 256 + n] : Wr[(k0 - 128) * 256 + n];
  float v1 = (k0 + 1 < 128) ? Wl[(k0 + 1) * 256 + n] : Wr[(k0 + 1 - 128) * 256 + n];
  Wf[gid] = pk2(v0, v1);
}

// ---------------- layer 0: gather-mean (bf16) + MFMA dense + relu ----------------
// 16 target rows per block, 4 waves. Gather: wave w aggregates rows w*4..w*4+3
// into A_lds cols 0..127 (bf16); self-features staged into cols 128..255.
// Then MFMA 16x16x32 bf16: M=16 rows, K=256, N=256 (wave w owns n-tiles w*4..w*4+3).
__global__ __launch_bounds__(256) void dense0_mfma(
    const float* __restrict__ x, const u32* __restrict__ xh,
    const int* __restrict__ off0, const int* __restrict__ esrc0,
    const u32* __restrict__ Wf, const float* __restrict__ bl,
    float* __restrict__ h) {
  // rows padded to 264 bf16 (528 B) -> 16B-aligned frag reads, 2-way banks (free)
  __shared__ __align__(16) unsigned short A_lds[16][264];
  const int tid = threadIdx.x;
  const int base = blockIdx.x * 16;
  const int wave = tid >> 6;
  const int lane = tid & 63;

  // stage self-features: thread handles row tid>>4, channels (tid&15)*8..+7
  {
    int r = tid >> 4;
    int cg = (tid & 15) * 8;
    const float4* xp = (const float4*)(x + (long long)(base + r) * INF + cg);
    float4 a = xp[0], b = xp[1];
    u32 o[4];
    o[0] = pk2(a.x, a.y); o[1] = pk2(a.z, a.w);
    o[2] = pk2(b.x, b.y); o[3] = pk2(b.z, b.w);
    *(uint4*)&A_lds[r][128 + cg] = *(const uint4*)o;
  }

  // gather-mean from packed-bf16 x; lane covers channels 2*lane, 2*lane+1
  for (int q = 0; q < 4; q++) {
    int r = wave * 4 + q;
    int row = base + r;
    int s0 = off0[row];
    int n = off0[row + 1] - s0;
    float accL = 0.f, accH = 0.f;
    for (int c0 = 0; c0 < n; c0 += 64) {
      int m = n - c0; if (m > 64) m = 64;
      int myid = (lane < m) ? esrc0[s0 + c0 + lane] : 0;
      int j = 0;
      for (; j + 8 <= m; j += 8) {
        int i0 = __shfl(myid, j + 0, 64);
        int i1 = __shfl(myid, j + 1, 64);
        int i2 = __shfl(myid, j + 2, 64);
        int i3 = __shfl(myid, j + 3, 64);
        int i4 = __shfl(myid, j + 4, 64);
        int i5 = __shfl(myid, j + 5, 64);
        int i6 = __shfl(myid, j + 6, 64);
        int i7 = __shfl(myid, j + 7, 64);
        u32 u0 = xh[i0 * 64 + lane];
        u32 u1 = xh[i1 * 64 + lane];
        u32 u2 = xh[i2 * 64 + lane];
        u32 u3 = xh[i3 * 64 + lane];
        u32 u4 = xh[i4 * 64 + lane];
        u32 u5 = xh[i5 * 64 + lane];
        u32 u6 = xh[i6 * 64 + lane];
        u32 u7 = xh[i7 * 64 + lane];
        accL += __uint_as_float(u0 << 16) + __uint_as_float(u1 << 16) +
                __uint_as_float(u2 << 16) + __uint_as_float(u3 << 16) +
                __uint_as_float(u4 << 16) + __uint_as_float(u5 << 16) +
                __uint_as_float(u6 << 16) + __uint_as_float(u7 << 16);
        accH += __uint_as_float(u0 & 0xffff0000u) + __uint_as_float(u1 & 0xffff0000u) +
                __uint_as_float(u2 & 0xffff0000u) + __uint_as_float(u3 & 0xffff0000u) +
                __uint_as_float(u4 & 0xffff0000u) + __uint_as_float(u5 & 0xffff0000u) +
                __uint_as_float(u6 & 0xffff0000u) + __uint_as_float(u7 & 0xffff0000u);
      }
      for (; j < m; j++) {
        int sid = __shfl(myid, j, 64);
        u32 u = xh[sid * 64 + lane];
        accL += __uint_as_float(u << 16);
        accH += __uint_as_float(u & 0xffff0000u);
      }
    }
    float rinv = 1.f / fmaxf((float)n, 1.f);
    *(u32*)&A_lds[r][2 * lane] = pk2(accL * rinv, accH * rinv);
  }
  __syncthreads();

  // MFMA phase: A-frag lane mapping m=lane&15, k = s*32 + (lane>>4)*8 + j
  const int m = lane & 15;
  const int quad = lane >> 4;
  f32x4 acc[4];
#pragma unroll
  for (int ti = 0; ti < 4; ti++) acc[ti] = (f32x4){0.f, 0.f, 0.f, 0.f};

  const bf16x8* Wf8 = (const bf16x8*)Wf;
  for (int s = 0; s < 8; s++) {
    bf16x8 af = *(const bf16x8*)&A_lds[m][s * 32 + quad * 8];
#pragma unroll
    for (int ti = 0; ti < 4; ti++) {
      int t = wave * 4 + ti;
      bf16x8 bfr = Wf8[(t * 8 + s) * 64 + lane];
      acc[ti] = __builtin_amdgcn_mfma_f32_16x16x32_bf16(af, bfr, acc[ti], 0, 0, 0);
    }
  }

  // C/D layout: col = lane&15, row = (lane>>4)*4 + reg
#pragma unroll
  for (int ti = 0; ti < 4; ti++) {
    int t = wave * 4 + ti;
    int n = t * 16 + m;
    float b = bl[n];
#pragma unroll
    for (int reg = 0; reg < 4; reg++) {
      int row = base + quad * 4 + reg;
      h[(long long)row * HIDF + n] = fmaxf(acc[ti][reg] + b, 0.0f);
    }
  }
}

// ---------------- layer 0 fallback (fp32 gather, VALU dense) ----------------
__global__ __launch_bounds__(256) void dense0_fused_f32(
    const float* __restrict__ x, const int* __restrict__ off0,
    const int* __restrict__ esrc0, const float* __restrict__ Wl,
    const float* __restrict__ bl, const float* __restrict__ Wr,
    float* __restrict__ h) {
  __shared__ float a_s[16 * 128];
  __shared__ float x_s[16 * 128];
  const int tid = threadIdx.x;
  const int base = blockIdx.x * 16;
  const int wave = tid >> 6;
  const int lane = tid & 63;

  for (int idx = tid; idx < 16 * 128; idx += 256)
    x_s[idx] = x[base * 128 + idx];

  for (int q = 0; q < 4; q++) {
    int r = wave * 4 + q;
    int row = base + r;
    int s0 = off0[row];
    int n = off0[row + 1] - s0;
    float acc0 = 0.f, acc1 = 0.f;
    for (int c0 = 0; c0 < n; c0 += 64) {
      int m = n - c0; if (m > 64) m = 64;
      int myid = (lane < m) ? esrc0[s0 + c0 + lane] : 0;
      for (int j = 0; j < m; j++) {
        int sid = __shfl(myid, j, 64);
        const float* xr = x + (long long)sid * INF;
        acc0 += xr[lane];
        acc1 += xr[lane + 64];
      }
    }
    float rinv = 1.f / fmaxf((float)n, 1.f);
    a_s[r * 128 + lane] = acc0 * rinv;
    a_s[r * 128 + lane + 64] = acc1 * rinv;
  }
  __syncthreads();

  const int j = tid;
  float acc[16];
#pragma unroll
  for (int rr = 0; rr < 16; rr++) acc[rr] = 0.0f;
  for (int k = 0; k < 128; k++) {
    float wl = Wl[k * 256 + j];
    float wr = Wr[k * 256 + j];
#pragma unroll
    for (int rr = 0; rr < 16; rr++)
      acc[rr] += a_s[rr * 128 + k] * wl + x_s[rr * 128 + k] * wr;
  }
  float b = bl[j];
#pragma unroll
  for (int rr = 0; rr < 16; rr++)
    h[(base + rr) * 256 + j] = fmaxf(acc[rr] + b, 0.0f);
}

// ---------------- layer 1: fused gather-mean + dense + log_softmax ----------------
__global__ __launch_bounds__(64) void final_fused(
    const float* __restrict__ h, const int* __restrict__ off1,
    const int* __restrict__ esrc1, const float* __restrict__ Wl,
    const float* __restrict__ bl, const float* __restrict__ Wr,
    float* __restrict__ out) {
  __shared__ float a_s[256];
  __shared__ float h_s[256];
  const int i = blockIdx.x;
  const int lane = threadIdx.x;

  int s0 = off1[i];
  int n = off1[i + 1] - s0;
  float acc0 = 0.f, acc1 = 0.f, acc2 = 0.f, acc3 = 0.f;
  for (int c0 = 0; c0 < n; c0 += 64) {
    int m = n - c0; if (m > 64) m = 64;
    int myid = (lane < m) ? esrc1[s0 + c0 + lane] : 0;
    int j = 0;
    for (; j + 2 <= m; j += 2) {
      int i0 = __shfl(myid, j, 64);
      int i1 = __shfl(myid, j + 1, 64);
      const float* r0 = h + (long long)i0 * HIDF;
      const float* r1 = h + (long long)i1 * HIDF;
      float a0 = r0[lane], b0 = r0[lane + 64], c0v = r0[lane + 128], d0 = r0[lane + 192];
      float a1 = r1[lane], b1 = r1[lane + 64], c1v = r1[lane + 128], d1 = r1[lane + 192];
      acc0 += a0 + a1; acc1 += b0 + b1; acc2 += c0v + c1v; acc3 += d0 + d1;
    }
    for (; j < m; j++) {
      int sid = __shfl(myid, j, 64);
      const float* hr = h + (long long)sid * HIDF;
      acc0 += hr[lane];
      acc1 += hr[lane + 64];
      acc2 += hr[lane + 128];
      acc3 += hr[lane + 192];
    }
  }
  float rinv = 1.f / fmaxf((float)n, 1.f);
  a_s[lane] = acc0 * rinv;
  a_s[lane + 64] = acc1 * rinv;
  a_s[lane + 128] = acc2 * rinv;
  a_s[lane + 192] = acc3 * rinv;
  const float* ht = h + (long long)i * HIDF;
  h_s[lane] = ht[lane];
  h_s[lane + 64] = ht[lane + 64];
  h_s[lane + 128] = ht[lane + 128];
  h_s[lane + 192] = ht[lane + 192];
  __syncthreads();

  float val = -INFINITY;
  if (lane < OUTF) {
    float acc = bl[lane];
    for (int k = 0; k < 256; k++)
      acc += a_s[k] * Wl[k * OUTF + lane] + h_s[k] * Wr[k * OUTF + lane];
    val = acc;
  }

  float mx = val;
  for (int off = 32; off >= 1; off >>= 1) mx = fmaxf(mx, __shfl_xor(mx, off, 64));
  float ex = (lane < OUTF) ? expf(val - mx) : 0.0f;
  float ssum = ex;
  for (int off = 32; off >= 1; off >>= 1) ssum += __shfl_xor(ssum, off, 64);

  if (lane < OUTF) out[i * OUTF + lane] = val - mx - logf(ssum);
}

extern "C" void kernel_launch(void* const* d_in, const int* in_sizes, int n_in,
                              void* d_out, int out_size, void* d_ws, size_t ws_size,
                              hipStream_t stream) {
  const float* x   = (const float*)d_in[0];
  const float* Wl0 = (const float*)d_in[1];
  const float* bl0 = (const float*)d_in[2];
  const float* Wr0 = (const float*)d_in[3];
  const float* Wl1 = (const float*)d_in[4];
  const float* bl1 = (const float*)d_in[5];
  const float* Wr1 = (const float*)d_in[6];
  const int* src0  = (const int*)d_in[7];
  const int* dst0  = (const int*)d_in[8];
  const int* src1  = (const int*)d_in[9];
  const int* dst1  = (const int*)d_in[10];
  float* out = (float*)d_out;

  // workspace layout (bytes):
  //   hist0 @ 0           200,000
  //   hist1 @ 200,064      16,384   (memset covers [0, 216,448))
  //   off0  @ 216,576     200,004
  //   cur0  @ 416,768     200,000
  //   off1  @ 616,960      16,388
  //   cur1  @ 633,600      16,384
  //   esrc0 @ 650,240   5,120,000
  //   esrc1 @ 5,770,240   163,840
  //   h     @ 5,934,080  51,200,000  (end 57,134,080)
  //   xh    @ 57,134,080 128,000,000 (end 185,134,080) -- mfma path
  //   Wf0   @ 185,134,080   131,072  (end 185,265,152) -- mfma path
  char* ws = (char*)d_ws;
  int* hist0 = (int*)(ws);
  int* hist1 = (int*)(ws + 200064);
  int* off0  = (int*)(ws + 216576);
  int* cur0  = (int*)(ws + 416768);
  int* off1  = (int*)(ws + 616960);
  int* cur1  = (int*)(ws + 633600);
  int* esrc0 = (int*)(ws + 650240);
  int* esrc1 = (int*)(ws + 5770240);
  float* h   = (float*)(ws + 5934080);
  u32* xh    = (u32*)(ws + 57134080);
  u32* Wf0   = (u32*)(ws + 185134080);

  const bool use_mfma = (ws_size >= (size_t)185265152);

  hipMemsetAsync(ws, 0, 216448, stream);

  const int gridE = (E0V + E1V + 255) / 256;
  hist_k<<<gridE, 256, 0, stream>>>(dst0, dst1, hist0, hist1);
  scan_k<<<1, 1024, 0, stream>>>(hist0, hist1, off0, cur0, off1, cur1);
  scatteridx_k<<<gridE, 256, 0, stream>>>(src0, dst0, src1, dst1,
                                          cur0, cur1, esrc0, esrc1);
  if (use_mfma) {
    conv_k<<<31250, 256, 0, stream>>>((const float4*)x, (uint4*)xh);
    packW0_k<<<128, 256, 0, stream>>>(Wl0, Wr0, Wf0);
    dense0_mfma<<<N1V / 16, 256, 0, stream>>>(x, xh, off0, esrc0, Wf0, bl0, h);
  } else {
    dense0_fused_f32<<<N1V / 16, 256, 0, stream>>>(x, off0, esrc0,
                                                   Wl0, bl0, Wr0, h);
  }
  final_fused<<<N2V, 64, 0, stream>>>(h, off1, esrc1, Wl1, bl1, Wr1, out);
}

// Round 6
// 741.700 us; speedup vs baseline: 1.2430x; 1.0337x over previous
//
#include <hip/hip_runtime.h>
#include <math.h>

typedef unsigned int u32;
typedef short bf16x8 __attribute__((ext_vector_type(8)));   // 8 bf16 bit-patterns
typedef float f32x4 __attribute__((ext_vector_type(4)));

#define N0V 500000
#define N1V 50000
#define N2V 4096
#define E0V 1280000
#define E1V 40960
#define INF 128
#define HIDF 256
#define OUTF 47

// merged prep kernel block ranges
#define CONV_BLOCKS 31250                      // 8,000,000 chunks / 256
#define HIST_BLOCKS 5160                       // 1,320,960 edges / 256
#define PACKW_BLOCKS 128

__device__ __forceinline__ u32 bf16rne(float f) {
  u32 u = __float_as_uint(f);
  return (u + 0x7fffu + ((u >> 16) & 1u)) >> 16;
}
__device__ __forceinline__ u32 pk2(float lo, float hi) {
  return bf16rne(lo) | (bf16rne(hi) << 16);
}

// ---------------- merged: x->bf16 conv | dst histogram | W0 pack ----------------
__global__ __launch_bounds__(256) void prep_k(
    const float4* __restrict__ x4, uint4* __restrict__ xh4,
    const int* __restrict__ dst0, const int* __restrict__ dst1,
    int* __restrict__ hist0, int* __restrict__ hist1,
    const float* __restrict__ Wl, const float* __restrict__ Wr,
    u32* __restrict__ Wf) {
  const int b = blockIdx.x;
  const int tid = threadIdx.x;
  if (b < CONV_BLOCKS) {
    int gid = b * 256 + tid;                 // < 8,000,000 exactly
    float4 a = x4[2 * gid];
    float4 c = x4[2 * gid + 1];
    uint4 o;
    o.x = pk2(a.x, a.y);
    o.y = pk2(a.z, a.w);
    o.z = pk2(c.x, c.y);
    o.w = pk2(c.z, c.w);
    xh4[gid] = o;
  } else if (b < CONV_BLOCKS + HIST_BLOCKS) {
    int gid = (b - CONV_BLOCKS) * 256 + tid; // < 1,320,960 exactly
    if (gid < E0V) {
      atomicAdd(&hist0[dst0[gid]], 1);
    } else {
      atomicAdd(&hist1[dst1[gid - E0V]], 1);
    }
  } else {
    // pack stacked [Wl;Wr] (256x256) into B-fragment order for 16x16x32 bf16:
    // lane holds B[k = s*32 + (lane>>4)*8 + j][n = t*16 + (lane&15)], j=0..7
    // layout: Wf[((t*8+s)*64 + lane)*8 + j]
    int gid = (b - CONV_BLOCKS - HIST_BLOCKS) * 256 + tid;  // 0..32767
    int e0 = 2 * gid;
    int j = e0 & 7;
    int lane = (e0 >> 3) & 63;
    int sq = e0 >> 9;
    int s = sq & 7;
    int t = sq >> 3;
    int n = t * 16 + (lane & 15);
    int k0 = s * 32 + (lane >> 4) * 8 + j;
    float v0 = (k0 < 128) ? Wl[k0 * 256 + n] : Wr[(k0 - 128) * 256 + n];
    float v1 = (k0 + 1 < 128) ? Wl[(k0 + 1) * 256 + n] : Wr[(k0 + 1 - 128) * 256 + n];
    Wf[gid] = pk2(v0, v1);
  }
}

// ---------------- CSR build: prefix scan (single block) ----------------
__global__ __launch_bounds__(1024) void scan_k(
    const int* __restrict__ hist0, const int* __restrict__ hist1,
    int* __restrict__ off0, int* __restrict__ cur0,
    int* __restrict__ off1, int* __restrict__ cur1) {
  __shared__ int sums[1024];
  const int t = threadIdx.x;
  {
    const int N = 50000, C = 49;
    int lo = t * C;
    int hi = lo + C; if (hi > N) hi = N;
    int s = 0;
    for (int i = lo; i < hi; i++) s += hist0[i];
    sums[t] = s;
    __syncthreads();
    for (int off = 1; off < 1024; off <<= 1) {
      int v = (t >= off) ? sums[t - off] : 0;
      __syncthreads();
      sums[t] += v;
      __syncthreads();
    }
    int run = sums[t] - s;
    for (int i = lo; i < hi; i++) {
      off0[i] = run; cur0[i] = run;
      run += hist0[i];
    }
    if (t == 1023) off0[N] = sums[1023];
    __syncthreads();
  }
  {
    const int N = 4096, C = 4;
    int lo = t * C;
    int hi = lo + C; if (hi > N) hi = N;
    int s = 0;
    for (int i = lo; i < hi; i++) s += hist1[i];
    sums[t] = s;
    __syncthreads();
    for (int off = 1; off < 1024; off <<= 1) {
      int v = (t >= off) ? sums[t - off] : 0;
      __syncthreads();
      sums[t] += v;
      __syncthreads();
    }
    int run = sums[t] - s;
    for (int i = lo; i < hi; i++) {
      off1[i] = run; cur1[i] = run;
      run += hist1[i];
    }
    if (t == 1023) off1[N] = sums[1023];
  }
}

// ---------------- CSR build: scatter edge source ids ----------------
__global__ __launch_bounds__(256) void scatteridx_k(
    const int* __restrict__ src0, const int* __restrict__ dst0,
    const int* __restrict__ src1, const int* __restrict__ dst1,
    int* __restrict__ cur0, int* __restrict__ cur1,
    int* __restrict__ esrc0, int* __restrict__ esrc1) {
  int gid = blockIdx.x * 256 + threadIdx.x;
  if (gid < E0V) {
    int pos = atomicAdd(&cur0[dst0[gid]], 1);
    esrc0[pos] = src0[gid];
  } else if (gid < E0V + E1V) {
    int g = gid - E0V;
    int pos = atomicAdd(&cur1[dst1[g]], 1);
    esrc1[pos] = src1[g];
  }
}

// ---------------- layer 0: scalar-indexed gather-mean + MFMA dense + relu ----------------
// 16 target rows/block, 4 waves; wave w aggregates rows w*4..w*4+3 into bf16 A_lds
// cols 0..127; self-features in cols 128..255. Then 16x16x32 bf16 MFMA, K=256, N=256.
__global__ __launch_bounds__(256) void dense0_mfma(
    const float* __restrict__ x, const u32* __restrict__ xh,
    const int* __restrict__ off0, const int* __restrict__ esrc0,
    const u32* __restrict__ Wf, const float* __restrict__ bl,
    float* __restrict__ h) {
  __shared__ __align__(16) unsigned short A_lds[16][264];
  const int tid = threadIdx.x;
  const int base = blockIdx.x * 16;
  const int wave = __builtin_amdgcn_readfirstlane(tid >> 6);  // wave-uniform
  const int lane = tid & 63;

  // self-features: thread -> row tid>>4, channels (tid&15)*8..+7
  {
    int r = tid >> 4;
    int cg = (tid & 15) * 8;
    const float4* xp = (const float4*)(x + (long long)(base + r) * INF + cg);
    float4 a = xp[0], b = xp[1];
    u32 o[4];
    o[0] = pk2(a.x, a.y); o[1] = pk2(a.z, a.w);
    o[2] = pk2(b.x, b.y); o[3] = pk2(b.z, b.w);
    *(uint4*)&A_lds[r][128 + cg] = *(const uint4*)o;
  }

  // gather-mean; edge ids fetched via wave-uniform (scalar) loads,
  // row data via SGPR-base + lane*4 loads, 16-deep pipeline.
  for (int q = 0; q < 4; q++) {
    int r = wave * 4 + q;
    int row = base + r;
    int s0 = __builtin_amdgcn_readfirstlane(off0[row]);
    int n  = __builtin_amdgcn_readfirstlane(off0[row + 1]) - s0;
    const int* e = esrc0 + s0;
    float accL = 0.f, accH = 0.f;
    int j = 0;
    for (; j + 16 <= n; j += 16) {
      u32 uu[16];
#pragma unroll
      for (int u = 0; u < 16; u++) {
        int sid = e[j + u];
        uu[u] = xh[(long long)sid * 64 + lane];
      }
#pragma unroll
      for (int u = 0; u < 16; u++) {
        accL += __uint_as_float(uu[u] << 16);
        accH += __uint_as_float(uu[u] & 0xffff0000u);
      }
    }
    for (; j + 4 <= n; j += 4) {
      u32 uu[4];
#pragma unroll
      for (int u = 0; u < 4; u++) {
        int sid = e[j + u];
        uu[u] = xh[(long long)sid * 64 + lane];
      }
#pragma unroll
      for (int u = 0; u < 4; u++) {
        accL += __uint_as_float(uu[u] << 16);
        accH += __uint_as_float(uu[u] & 0xffff0000u);
      }
    }
    for (; j < n; j++) {
      int sid = e[j];
      u32 u = xh[(long long)sid * 64 + lane];
      accL += __uint_as_float(u << 16);
      accH += __uint_as_float(u & 0xffff0000u);
    }
    float rinv = 1.f / fmaxf((float)n, 1.f);
    *(u32*)&A_lds[r][2 * lane] = pk2(accL * rinv, accH * rinv);
  }
  __syncthreads();

  // MFMA: A-frag m=lane&15, k = s*32 + (lane>>4)*8 + j
  const int m = lane & 15;
  const int quad = lane >> 4;
  f32x4 acc[4];
#pragma unroll
  for (int ti = 0; ti < 4; ti++) acc[ti] = (f32x4){0.f, 0.f, 0.f, 0.f};

  const bf16x8* Wf8 = (const bf16x8*)Wf;
  for (int s = 0; s < 8; s++) {
    bf16x8 af = *(const bf16x8*)&A_lds[m][s * 32 + quad * 8];
#pragma unroll
    for (int ti = 0; ti < 4; ti++) {
      int t = wave * 4 + ti;
      bf16x8 bfr = Wf8[(t * 8 + s) * 64 + lane];
      acc[ti] = __builtin_amdgcn_mfma_f32_16x16x32_bf16(af, bfr, acc[ti], 0, 0, 0);
    }
  }

  // C/D layout: col = lane&15, row = (lane>>4)*4 + reg
#pragma unroll
  for (int ti = 0; ti < 4; ti++) {
    int t = wave * 4 + ti;
    int n = t * 16 + m;
    float b = bl[n];
#pragma unroll
    for (int reg = 0; reg < 4; reg++) {
      int row = base + quad * 4 + reg;
      h[(long long)row * HIDF + n] = fmaxf(acc[ti][reg] + b, 0.0f);
    }
  }
}

// ---------------- layer 1: scalar-indexed gather-mean + dense + log_softmax ----------------
__global__ __launch_bounds__(64) void final_fused(
    const float* __restrict__ h, const int* __restrict__ off1,
    const int* __restrict__ esrc1, const float* __restrict__ Wl,
    const float* __restrict__ bl, const float* __restrict__ Wr,
    float* __restrict__ out) {
  __shared__ float a_s[256];
  __shared__ float h_s[256];
  const int i = blockIdx.x;
  const int lane = threadIdx.x;

  int s0 = __builtin_amdgcn_readfirstlane(off1[i]);
  int n  = __builtin_amdgcn_readfirstlane(off1[i + 1]) - s0;
  const int* e = esrc1 + s0;
  float acc0 = 0.f, acc1 = 0.f, acc2 = 0.f, acc3 = 0.f;
  int j = 0;
  for (; j + 4 <= n; j += 4) {
    float v[16];
#pragma unroll
    for (int u = 0; u < 4; u++) {
      const float* hr = h + (long long)e[j + u] * HIDF;
      v[4 * u + 0] = hr[lane];
      v[4 * u + 1] = hr[lane + 64];
      v[4 * u + 2] = hr[lane + 128];
      v[4 * u + 3] = hr[lane + 192];
    }
#pragma unroll
    for (int u = 0; u < 4; u++) {
      acc0 += v[4 * u + 0];
      acc1 += v[4 * u + 1];
      acc2 += v[4 * u + 2];
      acc3 += v[4 * u + 3];
    }
  }
  for (; j < n; j++) {
    const float* hr = h + (long long)e[j] * HIDF;
    acc0 += hr[lane];
    acc1 += hr[lane + 64];
    acc2 += hr[lane + 128];
    acc3 += hr[lane + 192];
  }
  float rinv = 1.f / fmaxf((float)n, 1.f);
  a_s[lane] = acc0 * rinv;
  a_s[lane + 64] = acc1 * rinv;
  a_s[lane + 128] = acc2 * rinv;
  a_s[lane + 192] = acc3 * rinv;
  const float* ht = h + (long long)i * HIDF;
  h_s[lane] = ht[lane];
  h_s[lane + 64] = ht[lane + 64];
  h_s[lane + 128] = ht[lane + 128];
  h_s[lane + 192] = ht[lane + 192];
  __syncthreads();

  float val = -INFINITY;
  if (lane < OUTF) {
    float acc = bl[lane];
    for (int k = 0; k < 256; k++)
      acc += a_s[k] * Wl[k * OUTF + lane] + h_s[k] * Wr[k * OUTF + lane];
    val = acc;
  }

  float mx = val;
  for (int off = 32; off >= 1; off >>= 1) mx = fmaxf(mx, __shfl_xor(mx, off, 64));
  float ex = (lane < OUTF) ? expf(val - mx) : 0.0f;
  float ssum = ex;
  for (int off = 32; off >= 1; off >>= 1) ssum += __shfl_xor(ssum, off, 64);

  if (lane < OUTF) out[i * OUTF + lane] = val - mx - logf(ssum);
}

extern "C" void kernel_launch(void* const* d_in, const int* in_sizes, int n_in,
                              void* d_out, int out_size, void* d_ws, size_t ws_size,
                              hipStream_t stream) {
  const float* x   = (const float*)d_in[0];
  const float* Wl0 = (const float*)d_in[1];
  const float* bl0 = (const float*)d_in[2];
  const float* Wr0 = (const float*)d_in[3];
  const float* Wl1 = (const float*)d_in[4];
  const float* bl1 = (const float*)d_in[5];
  const float* Wr1 = (const float*)d_in[6];
  const int* src0  = (const int*)d_in[7];
  const int* dst0  = (const int*)d_in[8];
  const int* src1  = (const int*)d_in[9];
  const int* dst1  = (const int*)d_in[10];
  float* out = (float*)d_out;

  // workspace layout (bytes):
  //   hist0 @ 0           200,000
  //   hist1 @ 200,064      16,384   (memset covers [0, 216,448))
  //   off0  @ 216,576     200,004
  //   cur0  @ 416,768     200,000
  //   off1  @ 616,960      16,388
  //   cur1  @ 633,600      16,384
  //   esrc0 @ 650,240   5,120,000
  //   esrc1 @ 5,770,240   163,840
  //   h     @ 5,934,080  51,200,000  (end 57,134,080)
  //   xh    @ 57,134,080 128,000,000 (end 185,134,080)
  //   Wf0   @ 185,134,080   131,072  (end 185,265,152)
  char* ws = (char*)d_ws;
  int* hist0 = (int*)(ws);
  int* hist1 = (int*)(ws + 200064);
  int* off0  = (int*)(ws + 216576);
  int* cur0  = (int*)(ws + 416768);
  int* off1  = (int*)(ws + 616960);
  int* cur1  = (int*)(ws + 633600);
  int* esrc0 = (int*)(ws + 650240);
  int* esrc1 = (int*)(ws + 5770240);
  float* h   = (float*)(ws + 5934080);
  u32* xh    = (u32*)(ws + 57134080);
  u32* Wf0   = (u32*)(ws + 185134080);

  hipMemsetAsync(ws, 0, 216448, stream);

  prep_k<<<CONV_BLOCKS + HIST_BLOCKS + PACKW_BLOCKS, 256, 0, stream>>>(
      (const float4*)x, (uint4*)xh, dst0, dst1, hist0, hist1, Wl0, Wr0, Wf0);
  scan_k<<<1, 1024, 0, stream>>>(hist0, hist1, off0, cur0, off1, cur1);
  scatteridx_k<<<(E0V + E1V + 255) / 256, 256, 0, stream>>>(
      src0, dst0, src1, dst1, cur0, cur1, esrc0, esrc1);
  dense0_mfma<<<N1V / 16, 256, 0, stream>>>(x, xh, off0, esrc0, Wf0, bl0, h);
  final_fused<<<N2V, 64, 0, stream>>>(h, off1, esrc1, Wl1, bl1, Wr1, out);
}